// Round 20
// baseline (464.591 us; speedup 1.0000x reference)
//
#include <hip/hip_runtime.h>
#include <hip/hip_bf16.h>
#include <hip/hip_fp16.h>

constexpr int N_ = 100000;
constexpr int E_ = 1600000;
constexpr int G_ = 1000;
constexpr int D_ = 128;
constexpr int C_ = 100;
constexpr int K_ = 2;
constexpr int L_ = 3;
constexpr int CAP_ = 64;                // padded CSR row capacity (max deg ~40)
constexpr int NR_ = 8;                  // XCD dst-ranges
constexpr int RN_ = N_ / NR_;           // 12500 nodes per range
constexpr int EPB_ = 1280;              // edges per chunk
constexpr int NCH_ = (E_ + EPB_ - 1) / EPB_; // 1250 chunks
constexpr int NGMAX_ = 8;               // max graphs spanned by a 128-node block

using f16x8 = __attribute__((ext_vector_type(8))) _Float16;
using f16x4 = __attribute__((ext_vector_type(4))) _Float16;
using f32x4 = __attribute__((ext_vector_type(4))) float;

// ---- one-pass padded CSR fill, XCD-partitioned (round-10 locality win) ----
__global__ __launch_bounds__(256) void fill_pad_xcd(
    const int* __restrict__ srcv, const int* __restrict__ dstv,
    int* __restrict__ cur, int* __restrict__ csr) {
    int r = blockIdx.x & 7;
    int chunk = blockIdx.x >> 3;
    int lo = r * RN_;
    int hi = lo + RN_;
    int ebeg = chunk * EPB_;
    int eend = ebeg + EPB_; if (eend > E_) eend = E_;
    for (int e = ebeg + threadIdx.x; e < eend; e += 256) {
        int d = dstv[e];
        if (d >= lo && d < hi) {
            int pos = atomicAdd(&cur[d], 1);
            if (pos < CAP_) csr[(size_t)d * CAP_ + pos] = srcv[e];
        }
    }
}

// ---- dis[n] = rsqrt(deg+1) ----
__global__ void dis_kernel(const int* __restrict__ cur, float* __restrict__ dis) {
    int i = blockIdx.x * 256 + threadIdx.x;
    if (i < N_) dis[i] = 1.0f / sqrtf((float)(cur[i] + 1));
}

// ---------------- embedding: h0 = fp16( x @ W_embed^T ) ----------------
__global__ __launch_bounds__(128) void embed_kernel(
    const float* __restrict__ x, const float* __restrict__ Wemb,
    _Float16* __restrict__ h) {
    __shared__ float4 xs[64 * 4];
    int t = threadIdx.x;                      // output dim d (0..127)
    float w[16];
#pragma unroll
    for (int f = 0; f < 16; ++f) w[f] = Wemb[t * 16 + f];
    int n0 = blockIdx.x * 64;
    const float4* x4 = (const float4*)x;
    for (int idx = t; idx < 64 * 4; idx += 128) {
        int gi = n0 * 4 + idx;
        xs[idx] = (gi < N_ * 4) ? x4[gi] : make_float4(0.f, 0.f, 0.f, 0.f);
    }
    __syncthreads();
    int lim = min(64, N_ - n0);
    for (int j = 0; j < lim; ++j) {
        float4 x0 = xs[j * 4 + 0], x1 = xs[j * 4 + 1];
        float4 x2 = xs[j * 4 + 2], x3 = xs[j * 4 + 3];
        float acc = x0.x * w[0] + x0.y * w[1] + x0.z * w[2] + x0.w * w[3]
                  + x1.x * w[4] + x1.y * w[5] + x1.z * w[6] + x1.w * w[7]
                  + x2.x * w[8] + x2.y * w[9] + x2.z * w[10] + x2.w * w[11]
                  + x3.x * w[12] + x3.y * w[13] + x3.z * w[14] + x3.w * w[15];
        h[(size_t)(n0 + j) * 128 + t] = (_Float16)acc;
    }
}

// ---------------- MFMA conv GEMM: mh = fp16(dis[n] * h@W^T) ----------------
__global__ __launch_bounds__(256) void mfma_gemm(
    const _Float16* __restrict__ h, const float* __restrict__ W,
    ushort* __restrict__ mh, const float* __restrict__ dis) {
    int t = threadIdx.x;
    int w = t >> 6;                    // wave 0..3
    int l = t & 63;
    int l15 = l & 15;
    int g = l >> 4;                    // 0..3
    int nb0 = blockIdx.x * 128;

    f16x8 afr[2][4];
#pragma unroll
    for (int cg = 0; cg < 2; ++cg) {
        int c = 16 * w + 64 * cg + l15;
#pragma unroll
        for (int ks = 0; ks < 4; ++ks) {
            const float* wp = &W[c * 128 + 32 * ks + 8 * g];
            float4 w0 = *(const float4*)wp;
            float4 w1 = *(const float4*)(wp + 4);
            f16x8 af;
            af[0] = (_Float16)w0.x; af[1] = (_Float16)w0.y;
            af[2] = (_Float16)w0.z; af[3] = (_Float16)w0.w;
            af[4] = (_Float16)w1.x; af[5] = (_Float16)w1.y;
            af[6] = (_Float16)w1.z; af[7] = (_Float16)w1.w;
            afr[cg][ks] = af;
        }
    }

    for (int nt = 0; nt < 8; ++nt) {
        int nb = nb0 + 16 * nt;
        int node = nb + l15;
        int nodeL = node < N_ ? node : 0;
        f16x8 bfr[4];
#pragma unroll
        for (int ks = 0; ks < 4; ++ks)
            bfr[ks] = *(const f16x8*)&h[(size_t)nodeL * 128 + 32 * ks + 8 * g];
        f32x4 acc0 = {0.f, 0.f, 0.f, 0.f};
        f32x4 acc1 = {0.f, 0.f, 0.f, 0.f};
#pragma unroll
        for (int ks = 0; ks < 4; ++ks) {
            acc0 = __builtin_amdgcn_mfma_f32_16x16x32_f16(afr[0][ks], bfr[ks], acc0, 0, 0, 0);
            acc1 = __builtin_amdgcn_mfma_f32_16x16x32_f16(afr[1][ks], bfr[ks], acc1, 0, 0, 0);
        }
        if (node < N_) {
            int cb = 16 * w + 4 * g;
            float s = dis[node];
            __half2 p01 = __float22half2_rn(make_float2(acc0[0] * s, acc0[1] * s));
            __half2 p23 = __float22half2_rn(make_float2(acc0[2] * s, acc0[3] * s));
            uint2 u0;
            u0.x = *(unsigned int*)&p01; u0.y = *(unsigned int*)&p23;
            *(uint2*)&mh[(size_t)node * 128 + cb] = u0;
            __half2 q01 = __float22half2_rn(make_float2(acc1[0] * s, acc1[1] * s));
            __half2 q23 = __float22half2_rn(make_float2(acc1[2] * s, acc1[3] * s));
            uint2 u1;
            u1.x = *(unsigned int*)&q01; u1.y = *(unsigned int*)&q23;
            *(uint2*)&mh[(size_t)node * 128 + cb + 64] = u1;
        }
    }
}

// ---- MFMA dots + distance + LDS-graph-local pool (batch sorted) ----------
// Block handles 128 consecutive nodes -> spans <= ~3 graphs. Distances
// accumulate in an LDS [NGMAX][C] table (LDS atomics); one nonzero-only
// global-atomic flush per block. Each pooled row is touched by ~2-3 blocks
// total (vs 800 in the round-13 disaster).
__global__ __launch_bounds__(256) void mfma_dist_pool(
    const _Float16* __restrict__ h, const float* __restrict__ cent,
    const float* __restrict__ x2, const int* __restrict__ batch,
    float* __restrict__ pooled) {
    __shared__ float c2s[128];
    __shared__ float pl[NGMAX_][C_];
    int t = threadIdx.x;
    int w = t >> 6;
    int l = t & 63;
    int l15 = l & 15;
    int g = l >> 4;
    int nb0 = blockIdx.x * 128;

    // c2 of fp16-rounded centroids (cent is 51KB, L2-hot)
    if (t < 128) {
        float cv = 0.f;
        if (t < C_) {
#pragma unroll 4
            for (int k = 0; k < 128; ++k) {
                float v = (float)(_Float16)cent[t * 128 + k];
                cv += v * v;
            }
        }
        c2s[t] = cv;
    }
    for (int idx = t; idx < NGMAX_ * C_; idx += 256)
        ((float*)pl)[idx] = 0.f;
    __syncthreads();

    int g_base = batch[nb0 < N_ ? nb0 : N_ - 1];

    f16x8 afr[2][4];
#pragma unroll
    for (int cg = 0; cg < 2; ++cg) {
        int c = 16 * w + 64 * cg + l15;
#pragma unroll
        for (int ks = 0; ks < 4; ++ks) {
            f16x8 af = {0, 0, 0, 0, 0, 0, 0, 0};
            if (c < C_) {
                const float* wp = &cent[c * 128 + 32 * ks + 8 * g];
                float4 w0 = *(const float4*)wp;
                float4 w1 = *(const float4*)(wp + 4);
                af[0] = (_Float16)w0.x; af[1] = (_Float16)w0.y;
                af[2] = (_Float16)w0.z; af[3] = (_Float16)w0.w;
                af[4] = (_Float16)w1.x; af[5] = (_Float16)w1.y;
                af[6] = (_Float16)w1.z; af[7] = (_Float16)w1.w;
            }
            afr[cg][ks] = af;
        }
    }

    for (int nt = 0; nt < 8; ++nt) {
        int nb = nb0 + 16 * nt;
        int node = nb + l15;
        int nodeL = node < N_ ? node : 0;
        f16x8 bfr[4];
#pragma unroll
        for (int ks = 0; ks < 4; ++ks)
            bfr[ks] = *(const f16x8*)&h[(size_t)nodeL * 128 + 32 * ks + 8 * g];
        f32x4 acc0 = {0.f, 0.f, 0.f, 0.f};
        f32x4 acc1 = {0.f, 0.f, 0.f, 0.f};
#pragma unroll
        for (int ks = 0; ks < 4; ++ks) {
            acc0 = __builtin_amdgcn_mfma_f32_16x16x32_f16(afr[0][ks], bfr[ks], acc0, 0, 0, 0);
            acc1 = __builtin_amdgcn_mfma_f32_16x16x32_f16(afr[1][ks], bfr[ks], acc1, 0, 0, 0);
        }
        if (node < N_) {
            float xv = x2[node];
            int gb = batch[node];
            int gl = gb - g_base;
            int cb = 16 * w + 4 * g;          // 0..63 always valid (< 100)
            if (gl >= 0 && gl < NGMAX_) {
#pragma unroll
                for (int j = 0; j < 4; ++j) {
                    float d = sqrtf(fmaxf(xv + c2s[cb + j] - 2.0f * acc0[j], 0.f) + 1e-12f);
                    atomicAdd(&pl[gl][cb + j], d);
                }
                int c1 = cb + 64;
                if (c1 < C_) {
#pragma unroll
                    for (int j = 0; j < 4; ++j) {
                        float d = sqrtf(fmaxf(xv + c2s[c1 + j] - 2.0f * acc1[j], 0.f) + 1e-12f);
                        atomicAdd(&pl[gl][c1 + j], d);
                    }
                }
            } else {                           // overflow fallback (never hit
#pragma unroll                                  // for this input's stats)
                for (int j = 0; j < 4; ++j) {
                    float d = sqrtf(fmaxf(xv + c2s[cb + j] - 2.0f * acc0[j], 0.f) + 1e-12f);
                    atomicAdd(&pooled[(size_t)gb * C_ + cb + j], d);
                }
                int c1 = cb + 64;
                if (c1 < C_) {
#pragma unroll
                    for (int j = 0; j < 4; ++j) {
                        float d = sqrtf(fmaxf(xv + c2s[c1 + j] - 2.0f * acc1[j], 0.f) + 1e-12f);
                        atomicAdd(&pooled[(size_t)gb * C_ + c1 + j], d);
                    }
                }
            }
        }
    }
    __syncthreads();
    // flush nonzero LDS sums; each graph row receives atomics from ~2 blocks
    for (int idx = t; idx < NGMAX_ * C_; idx += 256) {
        float v = ((float*)pl)[idx];
        if (v != 0.f) {
            int gl = idx / C_, c = idx - gl * C_;
            int gg = g_base + gl;
            if (gg < G_) atomicAdd(&pooled[(size_t)gg * C_ + c], v);
        }
    }
}

__device__ inline float4 h4f4(uint2 u) {
    float2 fa = __half22float2(*(__half2*)&u.x);
    float2 fb = __half22float2(*(__half2*)&u.y);
    return make_float4(fa.x, fa.y, fb.x, fb.y);
}

// ---------------- GCN aggregate over padded CSR (round-18 proven form) ----
__global__ __launch_bounds__(256) void aggregate(
    const ushort* __restrict__ mh, _Float16* __restrict__ hout,
    const int* __restrict__ cur, const int* __restrict__ csr,
    const float* __restrict__ dis, float* __restrict__ x2out) {
    int t = threadIdx.x;
    int lane = t & 63;
    int l32 = lane & 31;
    int hbase = lane & 32;                       // 0 | 32
    int node = blockIdx.x * 8 + ((t >> 6) << 1) + (hbase >> 5);   // N_ % 8 == 0
    const uint2* m2 = (const uint2*)mh;

    float4 acc0 = h4f4(m2[(size_t)node * 32 + l32]);   // self-loop term
    float4 acc1 = make_float4(0.f, 0.f, 0.f, 0.f);
    int deg = cur[node]; if (deg > CAP_) deg = CAP_;
    int beg = node * CAP_, end = beg + deg;
    for (int base = beg; base < end; base += 32) {
        int cnt = end - base; if (cnt > 32) cnt = 32;
        int myidx = (l32 < cnt) ? csr[base + l32] : 0;
        int j = 0;
        for (; j + 8 <= cnt; j += 8) {
            int s0 = __shfl(myidx, hbase + j);
            int s1 = __shfl(myidx, hbase + j + 1);
            int s2 = __shfl(myidx, hbase + j + 2);
            int s3 = __shfl(myidx, hbase + j + 3);
            int s4 = __shfl(myidx, hbase + j + 4);
            int s5 = __shfl(myidx, hbase + j + 5);
            int s6 = __shfl(myidx, hbase + j + 6);
            int s7 = __shfl(myidx, hbase + j + 7);
            uint2 u0 = m2[(size_t)s0 * 32 + l32];
            uint2 u1 = m2[(size_t)s1 * 32 + l32];
            uint2 u2 = m2[(size_t)s2 * 32 + l32];
            uint2 u3 = m2[(size_t)s3 * 32 + l32];
            uint2 u4 = m2[(size_t)s4 * 32 + l32];
            uint2 u5 = m2[(size_t)s5 * 32 + l32];
            uint2 u6 = m2[(size_t)s6 * 32 + l32];
            uint2 u7 = m2[(size_t)s7 * 32 + l32];
            float4 v0 = h4f4(u0), v1 = h4f4(u1), v2 = h4f4(u2), v3 = h4f4(u3);
            float4 v4 = h4f4(u4), v5 = h4f4(u5), v6 = h4f4(u6), v7 = h4f4(u7);
            acc0.x += (v0.x + v1.x) + (v2.x + v3.x);
            acc0.y += (v0.y + v1.y) + (v2.y + v3.y);
            acc0.z += (v0.z + v1.z) + (v2.z + v3.z);
            acc0.w += (v0.w + v1.w) + (v2.w + v3.w);
            acc1.x += (v4.x + v5.x) + (v6.x + v7.x);
            acc1.y += (v4.y + v5.y) + (v6.y + v7.y);
            acc1.z += (v4.z + v5.z) + (v6.z + v7.z);
            acc1.w += (v4.w + v5.w) + (v6.w + v7.w);
        }
        for (; j + 4 <= cnt; j += 4) {
            int s0 = __shfl(myidx, hbase + j);
            int s1 = __shfl(myidx, hbase + j + 1);
            int s2 = __shfl(myidx, hbase + j + 2);
            int s3 = __shfl(myidx, hbase + j + 3);
            uint2 u0 = m2[(size_t)s0 * 32 + l32];
            uint2 u1 = m2[(size_t)s1 * 32 + l32];
            uint2 u2 = m2[(size_t)s2 * 32 + l32];
            uint2 u3 = m2[(size_t)s3 * 32 + l32];
            float4 v0 = h4f4(u0), v1 = h4f4(u1), v2 = h4f4(u2), v3 = h4f4(u3);
            acc0.x += (v0.x + v1.x) + (v2.x + v3.x);
            acc0.y += (v0.y + v1.y) + (v2.y + v3.y);
            acc0.z += (v0.z + v1.z) + (v2.z + v3.z);
            acc0.w += (v0.w + v1.w) + (v2.w + v3.w);
        }
        for (; j < cnt; ++j) {
            int s = __shfl(myidx, hbase + j);
            float4 v = h4f4(m2[(size_t)s * 32 + l32]);
            acc1.x += v.x; acc1.y += v.y; acc1.z += v.z; acc1.w += v.w;
        }
    }
    float di = dis[node];
    f16x4 hq;
    hq[0] = (_Float16)fmaxf(di * (acc0.x + acc1.x), 0.f);
    hq[1] = (_Float16)fmaxf(di * (acc0.y + acc1.y), 0.f);
    hq[2] = (_Float16)fmaxf(di * (acc0.z + acc1.z), 0.f);
    hq[3] = (_Float16)fmaxf(di * (acc0.w + acc1.w), 0.f);
    *(f16x4*)&hout[(size_t)node * 128 + (l32 << 2)] = hq;
    if (x2out) {   // row norm of the fp16-ROUNDED h (consistent with dots GEMM)
        float h0 = (float)hq[0], h1 = (float)hq[1];
        float h2 = (float)hq[2], h3 = (float)hq[3];
        float p = h0 * h0 + h1 * h1 + h2 * h2 + h3 * h3;
        p += __shfl_xor(p, 1);
        p += __shfl_xor(p, 2);
        p += __shfl_xor(p, 4);
        p += __shfl_xor(p, 8);
        p += __shfl_xor(p, 16);
        if (l32 == 0) x2out[node] = p;
    }
}

// ---------------- final: out = (pool_sum/cnt) @ W_out^T + b_out ----------
__global__ void final_out(const float* __restrict__ pooled,
                          const int* __restrict__ batch,
                          const float* __restrict__ W_out, const float* __restrict__ b_out,
                          float* __restrict__ out) {
    int i = blockIdx.x * 256 + threadIdx.x;
    if (i >= G_ * K_) return;
    int g = i >> 1, k = i & 1;
    int lo = 0, hi = N_;
    while (lo < hi) { int mid = (lo + hi) >> 1; if (batch[mid] < g) lo = mid + 1; else hi = mid; }
    int s = lo;
    hi = N_;
    while (lo < hi) { int mid = (lo + hi) >> 1; if (batch[mid] < g + 1) lo = mid + 1; else hi = mid; }
    int e = lo;
    float inv = 1.0f / fmaxf((float)(e - s), 1.0f);
    float acc = 0.f;
    for (int c = 0; c < C_; ++c) acc += pooled[g * C_ + c] * W_out[k * C_ + c];
    out[i] = acc * inv + b_out[k];
}

extern "C" void kernel_launch(void* const* d_in, const int* in_sizes, int n_in,
                              void* d_out, int out_size, void* d_ws, size_t ws_size,
                              hipStream_t stream) {
    const float* x       = (const float*)d_in[0];
    const int*   eidx    = (const int*)d_in[1];    // [2][E]: src then dst
    const int*   batch   = (const int*)d_in[2];
    const float* W_embed = (const float*)d_in[3];
    const float* W_convs = (const float*)d_in[4];
    const float* cent    = (const float*)d_in[5];
    const float* W_out   = (const float*)d_in[6];
    const float* b_out   = (const float*)d_in[7];
    float* out = (float*)d_out;

    char* p = (char*)d_ws;
    _Float16* h  = (_Float16*)p; p += (size_t)N_ * D_ * 2;  // fp16 node features
    ushort* mh   = (ushort*)p; p += (size_t)N_ * D_ * 2;    // fp16 messages
    int*   cur  = (int*)p;   p += (size_t)N_ * 4;           // degree counters
    float* dis  = (float*)p; p += (size_t)N_ * 4;
    int*   csr  = (int*)p;   p += (size_t)N_ * CAP_ * 4;    // padded CSR 25.6MB
    float* x2   = (float*)p; p += (size_t)N_ * 4;
    float* pool = (float*)p; p += (size_t)G_ * C_ * 4;

    const int* esrc = eidx;
    const int* edst = eidx + E_;

    hipMemsetAsync(cur, 0, (size_t)N_ * 4, stream);
    hipMemsetAsync(pool, 0, (size_t)G_ * C_ * 4, stream);

    fill_pad_xcd<<<NR_ * NCH_, 256, 0, stream>>>(esrc, edst, cur, csr);
    dis_kernel<<<(N_ + 255) / 256, 256, 0, stream>>>(cur, dis);

    // h0 = fp16(x @ W_embed^T)
    embed_kernel<<<(N_ + 63) / 64, 128, 0, stream>>>(x, W_embed, h);

    int ngb = (N_ + 127) / 128;   // 782
    for (int l = 0; l < L_; ++l) {
        mfma_gemm<<<ngb, 256, 0, stream>>>(h, W_convs + (size_t)l * D_ * D_, mh, dis);
        aggregate<<<N_ / 8, 256, 0, stream>>>(mh, h, cur, csr, dis,
                                              (l == L_ - 1) ? x2 : nullptr);
    }

    // fused dots + distance + per-graph pooling (no dots materialization)
    mfma_dist_pool<<<ngb, 256, 0, stream>>>(h, cent, x2, batch, pool);
    final_out<<<(G_ * K_ + 255) / 256, 256, 0, stream>>>(pool, batch, W_out, b_out, out);
}

// Round 21
// 404.403 us; speedup vs baseline: 1.1488x; 1.1488x over previous
//
#include <hip/hip_runtime.h>
#include <hip/hip_bf16.h>
#include <hip/hip_fp16.h>

constexpr int N_ = 100000;
constexpr int E_ = 1600000;
constexpr int G_ = 1000;
constexpr int D_ = 128;
constexpr int C_ = 100;
constexpr int K_ = 2;
constexpr int L_ = 3;
constexpr int CAP_ = 64;                // padded CSR row capacity (max deg ~40)
constexpr int NR_ = 8;                  // XCD dst-ranges
constexpr int RN_ = N_ / NR_;           // 12500 nodes per range
constexpr int EPB_ = 1280;              // edges per chunk
constexpr int NCH_ = (E_ + EPB_ - 1) / EPB_; // 1250 chunks

using f16x8 = __attribute__((ext_vector_type(8))) _Float16;
using f16x4 = __attribute__((ext_vector_type(4))) _Float16;
using f32x4 = __attribute__((ext_vector_type(4))) float;

// ---- one-pass padded CSR fill, XCD-partitioned (round-10 locality win) ----
__global__ __launch_bounds__(256) void fill_pad_xcd(
    const int* __restrict__ srcv, const int* __restrict__ dstv,
    int* __restrict__ cur, int* __restrict__ csr) {
    int r = blockIdx.x & 7;
    int chunk = blockIdx.x >> 3;
    int lo = r * RN_;
    int hi = lo + RN_;
    int ebeg = chunk * EPB_;
    int eend = ebeg + EPB_; if (eend > E_) eend = E_;
    for (int e = ebeg + threadIdx.x; e < eend; e += 256) {
        int d = dstv[e];
        if (d >= lo && d < hi) {
            int pos = atomicAdd(&cur[d], 1);
            if (pos < CAP_) csr[(size_t)d * CAP_ + pos] = srcv[e];
        }
    }
}

// ---- dis[n] = rsqrt(deg+1) ----
__global__ void dis_kernel(const int* __restrict__ cur, float* __restrict__ dis) {
    int i = blockIdx.x * 256 + threadIdx.x;
    if (i < N_) dis[i] = 1.0f / sqrtf((float)(cur[i] + 1));
}

// ---------------- embedding: h0 = fp16( x @ W_embed^T ) ----------------
__global__ __launch_bounds__(128) void embed_kernel(
    const float* __restrict__ x, const float* __restrict__ Wemb,
    _Float16* __restrict__ h) {
    __shared__ float4 xs[64 * 4];
    int t = threadIdx.x;                      // output dim d (0..127)
    float w[16];
#pragma unroll
    for (int f = 0; f < 16; ++f) w[f] = Wemb[t * 16 + f];
    int n0 = blockIdx.x * 64;
    const float4* x4 = (const float4*)x;
    for (int idx = t; idx < 64 * 4; idx += 128) {
        int gi = n0 * 4 + idx;
        xs[idx] = (gi < N_ * 4) ? x4[gi] : make_float4(0.f, 0.f, 0.f, 0.f);
    }
    __syncthreads();
    int lim = min(64, N_ - n0);
    for (int j = 0; j < lim; ++j) {
        float4 x0 = xs[j * 4 + 0], x1 = xs[j * 4 + 1];
        float4 x2 = xs[j * 4 + 2], x3 = xs[j * 4 + 3];
        float acc = x0.x * w[0] + x0.y * w[1] + x0.z * w[2] + x0.w * w[3]
                  + x1.x * w[4] + x1.y * w[5] + x1.z * w[6] + x1.w * w[7]
                  + x2.x * w[8] + x2.y * w[9] + x2.z * w[10] + x2.w * w[11]
                  + x3.x * w[12] + x3.y * w[13] + x3.z * w[14] + x3.w * w[15];
        h[(size_t)(n0 + j) * 128 + t] = (_Float16)acc;
    }
}

// ---------------- MFMA GEMM: D[c][n] = sum_k W[c][k] * h[n][k] ----------
// FP16OUT=1: mh = fp16(dis[n]*out); FP16OUT=0: fp32 out (dots).
template<int FP16OUT>
__global__ __launch_bounds__(256) void mfma_gemm(
    const _Float16* __restrict__ h, const float* __restrict__ W,
    void* __restrict__ outp, int ncols, const float* __restrict__ dis) {
    int t = threadIdx.x;
    int w = t >> 6;                    // wave 0..3
    int l = t & 63;
    int l15 = l & 15;
    int g = l >> 4;                    // 0..3
    int nb0 = blockIdx.x * 128;

    f16x8 afr[2][4];
#pragma unroll
    for (int cg = 0; cg < 2; ++cg) {
        int c = 16 * w + 64 * cg + l15;
#pragma unroll
        for (int ks = 0; ks < 4; ++ks) {
            f16x8 af = {0, 0, 0, 0, 0, 0, 0, 0};
            if (c < ncols) {
                const float* wp = &W[c * 128 + 32 * ks + 8 * g];
                float4 w0 = *(const float4*)wp;
                float4 w1 = *(const float4*)(wp + 4);
                af[0] = (_Float16)w0.x; af[1] = (_Float16)w0.y;
                af[2] = (_Float16)w0.z; af[3] = (_Float16)w0.w;
                af[4] = (_Float16)w1.x; af[5] = (_Float16)w1.y;
                af[6] = (_Float16)w1.z; af[7] = (_Float16)w1.w;
            }
            afr[cg][ks] = af;
        }
    }

    for (int nt = 0; nt < 8; ++nt) {
        int nb = nb0 + 16 * nt;
        int node = nb + l15;
        int nodeL = node < N_ ? node : 0;
        f16x8 bfr[4];
#pragma unroll
        for (int ks = 0; ks < 4; ++ks)
            bfr[ks] = *(const f16x8*)&h[(size_t)nodeL * 128 + 32 * ks + 8 * g];
        f32x4 acc0 = {0.f, 0.f, 0.f, 0.f};
        f32x4 acc1 = {0.f, 0.f, 0.f, 0.f};
#pragma unroll
        for (int ks = 0; ks < 4; ++ks) {
            acc0 = __builtin_amdgcn_mfma_f32_16x16x32_f16(afr[0][ks], bfr[ks], acc0, 0, 0, 0);
            acc1 = __builtin_amdgcn_mfma_f32_16x16x32_f16(afr[1][ks], bfr[ks], acc1, 0, 0, 0);
        }
        if (node < N_) {
            int cb = 16 * w + 4 * g;
            if (FP16OUT) {
                float s = dis[node];
                ushort* mh = (ushort*)outp;
                __half2 p01 = __float22half2_rn(make_float2(acc0[0] * s, acc0[1] * s));
                __half2 p23 = __float22half2_rn(make_float2(acc0[2] * s, acc0[3] * s));
                uint2 u0;
                u0.x = *(unsigned int*)&p01; u0.y = *(unsigned int*)&p23;
                *(uint2*)&mh[(size_t)node * 128 + cb] = u0;
                __half2 q01 = __float22half2_rn(make_float2(acc1[0] * s, acc1[1] * s));
                __half2 q23 = __float22half2_rn(make_float2(acc1[2] * s, acc1[3] * s));
                uint2 u1;
                u1.x = *(unsigned int*)&q01; u1.y = *(unsigned int*)&q23;
                *(uint2*)&mh[(size_t)node * 128 + cb + 64] = u1;
            } else {
                float* o = (float*)outp;
                *(float4*)&o[(size_t)node * 128 + cb] =
                    make_float4(acc0[0], acc0[1], acc0[2], acc0[3]);
                *(float4*)&o[(size_t)node * 128 + cb + 64] =
                    make_float4(acc1[0], acc1[1], acc1[2], acc1[3]);
            }
        }
    }
}

__device__ inline float4 h4f4(uint2 u) {
    float2 fa = __half22float2(*(__half2*)&u.x);
    float2 fb = __half22float2(*(__half2*)&u.y);
    return make_float4(fa.x, fa.y, fb.x, fb.y);
}

// ---------------- GCN aggregate over padded CSR (round-18 proven form) ----
__global__ __launch_bounds__(256) void aggregate(
    const ushort* __restrict__ mh, _Float16* __restrict__ hout,
    const int* __restrict__ cur, const int* __restrict__ csr,
    const float* __restrict__ dis, float* __restrict__ x2out) {
    int t = threadIdx.x;
    int lane = t & 63;
    int l32 = lane & 31;
    int hbase = lane & 32;                       // 0 | 32
    int node = blockIdx.x * 8 + ((t >> 6) << 1) + (hbase >> 5);   // N_ % 8 == 0
    const uint2* m2 = (const uint2*)mh;

    float4 acc0 = h4f4(m2[(size_t)node * 32 + l32]);   // self-loop term
    float4 acc1 = make_float4(0.f, 0.f, 0.f, 0.f);
    int deg = cur[node]; if (deg > CAP_) deg = CAP_;
    int beg = node * CAP_, end = beg + deg;
    for (int base = beg; base < end; base += 32) {
        int cnt = end - base; if (cnt > 32) cnt = 32;
        int myidx = (l32 < cnt) ? csr[base + l32] : 0;
        int j = 0;
        for (; j + 8 <= cnt; j += 8) {
            int s0 = __shfl(myidx, hbase + j);
            int s1 = __shfl(myidx, hbase + j + 1);
            int s2 = __shfl(myidx, hbase + j + 2);
            int s3 = __shfl(myidx, hbase + j + 3);
            int s4 = __shfl(myidx, hbase + j + 4);
            int s5 = __shfl(myidx, hbase + j + 5);
            int s6 = __shfl(myidx, hbase + j + 6);
            int s7 = __shfl(myidx, hbase + j + 7);
            uint2 u0 = m2[(size_t)s0 * 32 + l32];
            uint2 u1 = m2[(size_t)s1 * 32 + l32];
            uint2 u2 = m2[(size_t)s2 * 32 + l32];
            uint2 u3 = m2[(size_t)s3 * 32 + l32];
            uint2 u4 = m2[(size_t)s4 * 32 + l32];
            uint2 u5 = m2[(size_t)s5 * 32 + l32];
            uint2 u6 = m2[(size_t)s6 * 32 + l32];
            uint2 u7 = m2[(size_t)s7 * 32 + l32];
            float4 v0 = h4f4(u0), v1 = h4f4(u1), v2 = h4f4(u2), v3 = h4f4(u3);
            float4 v4 = h4f4(u4), v5 = h4f4(u5), v6 = h4f4(u6), v7 = h4f4(u7);
            acc0.x += (v0.x + v1.x) + (v2.x + v3.x);
            acc0.y += (v0.y + v1.y) + (v2.y + v3.y);
            acc0.z += (v0.z + v1.z) + (v2.z + v3.z);
            acc0.w += (v0.w + v1.w) + (v2.w + v3.w);
            acc1.x += (v4.x + v5.x) + (v6.x + v7.x);
            acc1.y += (v4.y + v5.y) + (v6.y + v7.y);
            acc1.z += (v4.z + v5.z) + (v6.z + v7.z);
            acc1.w += (v4.w + v5.w) + (v6.w + v7.w);
        }
        for (; j + 4 <= cnt; j += 4) {
            int s0 = __shfl(myidx, hbase + j);
            int s1 = __shfl(myidx, hbase + j + 1);
            int s2 = __shfl(myidx, hbase + j + 2);
            int s3 = __shfl(myidx, hbase + j + 3);
            uint2 u0 = m2[(size_t)s0 * 32 + l32];
            uint2 u1 = m2[(size_t)s1 * 32 + l32];
            uint2 u2 = m2[(size_t)s2 * 32 + l32];
            uint2 u3 = m2[(size_t)s3 * 32 + l32];
            float4 v0 = h4f4(u0), v1 = h4f4(u1), v2 = h4f4(u2), v3 = h4f4(u3);
            acc0.x += (v0.x + v1.x) + (v2.x + v3.x);
            acc0.y += (v0.y + v1.y) + (v2.y + v3.y);
            acc0.z += (v0.z + v1.z) + (v2.z + v3.z);
            acc0.w += (v0.w + v1.w) + (v2.w + v3.w);
        }
        for (; j < cnt; ++j) {
            int s = __shfl(myidx, hbase + j);
            float4 v = h4f4(m2[(size_t)s * 32 + l32]);
            acc1.x += v.x; acc1.y += v.y; acc1.z += v.z; acc1.w += v.w;
        }
    }
    float di = dis[node];
    f16x4 hq;
    hq[0] = (_Float16)fmaxf(di * (acc0.x + acc1.x), 0.f);
    hq[1] = (_Float16)fmaxf(di * (acc0.y + acc1.y), 0.f);
    hq[2] = (_Float16)fmaxf(di * (acc0.z + acc1.z), 0.f);
    hq[3] = (_Float16)fmaxf(di * (acc0.w + acc1.w), 0.f);
    *(f16x4*)&hout[(size_t)node * 128 + (l32 << 2)] = hq;
    if (x2out) {   // row norm of the fp16-ROUNDED h (consistent with dots GEMM)
        float h0 = (float)hq[0], h1 = (float)hq[1];
        float h2 = (float)hq[2], h3 = (float)hq[3];
        float p = h0 * h0 + h1 * h1 + h2 * h2 + h3 * h3;
        p += __shfl_xor(p, 1);
        p += __shfl_xor(p, 2);
        p += __shfl_xor(p, 4);
        p += __shfl_xor(p, 8);
        p += __shfl_xor(p, 16);
        if (l32 == 0) x2out[node] = p;
    }
}

// ------- fused: c2 + per-graph mean-pool of distances + final GEMV --------
__global__ __launch_bounds__(128) void pool_final(
    const float* __restrict__ dots, const float* __restrict__ x2,
    const float* __restrict__ cent, const int* __restrict__ batch,
    const float* __restrict__ W_out, const float* __restrict__ b_out,
    float* __restrict__ out) {
    __shared__ float sp[128];
    int g = blockIdx.x;
    int t = threadIdx.x;
    int lo = 0, hi = N_;
    while (lo < hi) { int mid = (lo + hi) >> 1; if (batch[mid] < g) lo = mid + 1; else hi = mid; }
    int s = lo;
    hi = N_;
    while (lo < hi) { int mid = (lo + hi) >> 1; if (batch[mid] < g + 1) lo = mid + 1; else hi = mid; }
    int e = lo;
    float pooledv = 0.f;
    if (t < C_) {
        // c2 of fp16-rounded centroid row t (L2-hot, 51KB total)
        float cv = 0.f;
#pragma unroll 4
        for (int k = 0; k < 128; ++k) {
            float v = (float)(_Float16)cent[t * 128 + k];
            cv += v * v;
        }
        float a0 = 0.f, a1 = 0.f, a2 = 0.f, a3 = 0.f;
        int n = s;
        for (; n + 4 <= e; n += 4) {
            float d0 = dots[(size_t)(n    ) * 128 + t];
            float d1 = dots[(size_t)(n + 1) * 128 + t];
            float d2 = dots[(size_t)(n + 2) * 128 + t];
            float d3 = dots[(size_t)(n + 3) * 128 + t];
            float x0 = x2[n], x1 = x2[n + 1], x2v = x2[n + 2], x3 = x2[n + 3];
            a0 += sqrtf(fmaxf(x0  + cv - 2.f * d0, 0.f) + 1e-12f);
            a1 += sqrtf(fmaxf(x1  + cv - 2.f * d1, 0.f) + 1e-12f);
            a2 += sqrtf(fmaxf(x2v + cv - 2.f * d2, 0.f) + 1e-12f);
            a3 += sqrtf(fmaxf(x3  + cv - 2.f * d3, 0.f) + 1e-12f);
        }
        for (; n < e; ++n) {
            float d = dots[(size_t)n * 128 + t];
            a0 += sqrtf(fmaxf(x2[n] + cv - 2.f * d, 0.f) + 1e-12f);
        }
        float inv = 1.0f / fmaxf((float)(e - s), 1.0f);
        pooledv = (a0 + a1 + a2 + a3) * inv;
    }
    sp[t] = pooledv;
    __syncthreads();
    if (t < K_) {
        float acc = 0.f;
        for (int c = 0; c < C_; ++c) acc += sp[c] * W_out[t * C_ + c];
        out[g * K_ + t] = acc + b_out[t];
    }
}

extern "C" void kernel_launch(void* const* d_in, const int* in_sizes, int n_in,
                              void* d_out, int out_size, void* d_ws, size_t ws_size,
                              hipStream_t stream) {
    const float* x       = (const float*)d_in[0];
    const int*   eidx    = (const int*)d_in[1];    // [2][E]: src then dst
    const int*   batch   = (const int*)d_in[2];
    const float* W_embed = (const float*)d_in[3];
    const float* W_convs = (const float*)d_in[4];
    const float* cent    = (const float*)d_in[5];
    const float* W_out   = (const float*)d_in[6];
    const float* b_out   = (const float*)d_in[7];
    float* out = (float*)d_out;

    char* p = (char*)d_ws;
    _Float16* h  = (_Float16*)p; p += (size_t)N_ * D_ * 2;  // fp16 node features
    float*  dots = (float*)p;  p += (size_t)N_ * D_ * 4;    // fp32 h@cent^T
    ushort* mh   = (ushort*)p; p += (size_t)N_ * D_ * 2;    // fp16 messages
    int*   cur  = (int*)p;   p += (size_t)N_ * 4;           // degree counters
    float* dis  = (float*)p; p += (size_t)N_ * 4;
    int*   csr  = (int*)p;   p += (size_t)N_ * CAP_ * 4;    // padded CSR 25.6MB
    float* x2   = (float*)p; p += (size_t)N_ * 4;

    const int* esrc = eidx;
    const int* edst = eidx + E_;

    hipMemsetAsync(cur, 0, (size_t)N_ * 4, stream);

    fill_pad_xcd<<<NR_ * NCH_, 256, 0, stream>>>(esrc, edst, cur, csr);
    dis_kernel<<<(N_ + 255) / 256, 256, 0, stream>>>(cur, dis);

    // h0 = fp16(x @ W_embed^T)
    embed_kernel<<<(N_ + 63) / 64, 128, 0, stream>>>(x, W_embed, h);

    int ngb = (N_ + 127) / 128;   // 782
    for (int l = 0; l < L_; ++l) {
        mfma_gemm<1><<<ngb, 256, 0, stream>>>(h, W_convs + (size_t)l * D_ * D_,
                                              (void*)mh, 128, dis);
        aggregate<<<N_ / 8, 256, 0, stream>>>(mh, h, cur, csr, dis,
                                              (l == L_ - 1) ? x2 : nullptr);
    }

    // dots = h @ centroids^T (cols 100..127 zeroed via A-frag guard)
    mfma_gemm<0><<<ngb, 256, 0, stream>>>(h, cent, (void*)dots, 100, nullptr);
    pool_final<<<G_, 128, 0, stream>>>(dots, x2, cent, batch, W_out, b_out, out);
}